// Round 8
// baseline (102.615 us; speedup 1.0000x reference)
//
#include <hip/hip_runtime.h>
#include <hip/hip_bf16.h>
#include <stdint.h>

// SelfAttention: B=8, C=64, N=4096, d_k=8.
// out[b,c,m] = gamma * (sum_n h[b,c,n] * softmax_n(f[:,n].g[:,m])) + x[b,c,m]
//
// R8: attn is VALU-bound by v_exp_f32 (~16 cyc/wave64, measured via R3
// VALUBusy reconciliation); R7's remaining gap was exposed global latency
// inside each barrier interval. Now: loads issued 2 steps ahead into
// registers (~1200 cyc cover), ds_write 1 step after issue, 2 LDS buffers,
// unroll x2. lsum computed by an extra MFMA with a ones-B fragment
// (offloads 16 adds/iter from VALU to the idle mfma pipe).
//   QK: native 32x32x16, K padded 8->16 (qf zeroed in hh=1 lanes).
//   tau row-permute (l5^12 on groups 4-7<->8-11, 20-23<->24-27) on the K row
//   makes S^T regs 0..7/8..15 pack sequentially into PV A-frags (no shuffles).
// hswz (V) layout per 32-n tile (4096 B), 32x32x16 B-frag order:
//   offset = chunk*2048 + ct*1024 + (hh*32+l5)*16 holding
//   h[c=ct*32+l5][n = nb*32 + chunk*16 + 8*hh + j], j=0..7.
// K1 (fgh): MFMA projection (x read once), native 32x32x16 K-loop.

typedef short v4s __attribute__((ext_vector_type(4)));
typedef short v8s __attribute__((ext_vector_type(8)));
typedef float v16f __attribute__((ext_vector_type(16)));
typedef unsigned int v4u __attribute__((ext_vector_type(4)));
typedef unsigned int v2u __attribute__((ext_vector_type(2)));

__device__ __forceinline__ unsigned bf16pair(float lo, float hi) {
    unsigned a = __builtin_bit_cast(unsigned, lo) + 0x8000u;
    unsigned b = __builtin_bit_cast(unsigned, hi) + 0x8000u;
    return (a >> 16) | (b & 0xffff0000u);
}
__device__ __forceinline__ unsigned short bf16r(float x) {
    return (unsigned short)((__builtin_bit_cast(unsigned, x) + 0x8000u) >> 16);
}
// truncating bf16 pack via v_perm: dword = [hi16(hi) | hi16(lo)]
__device__ __forceinline__ unsigned packt(float lo, float hi) {
    return __builtin_amdgcn_perm(__builtin_bit_cast(unsigned, hi),
                                 __builtin_bit_cast(unsigned, lo), 0x07060302u);
}

// ---------------- K1: MFMA projection ----------------
// grid 1024 = (b<<7)|nb. Wave w<2: h rows w*32..+31; wave 2: f(0-7)+g(8-15).
__global__ __launch_bounds__(256) void fgh_kernel(
    const float* __restrict__ x, const float* __restrict__ Wq,
    const float* __restrict__ Wk, const float* __restrict__ Wv,
    unsigned int* __restrict__ ftgt,   // ft dwords [0,131072), gt [131072,262144)
    v4u* __restrict__ hswz)
{
    __shared__ v4u wfragN[768];        // 3 row-groups x 4 kb x 64 lanes x 16B
    __shared__ v4u xfragN[256];        // 4 kb x 64 lanes x 16B
    __shared__ short hbuf[64 * 36];    // [c][nloc] pad 36

    const int blk  = blockIdx.x;
    const int b    = blk >> 7;
    const int nb   = blk & 127;
    const int n0   = nb << 5;
    const int tid  = threadIdx.x;
    const int wave = tid >> 6;
    const int lane = tid & 63;
    const int l5   = lane & 31;
    const int hh   = lane >> 5;

    const float* xb = x + (size_t)b * 262144 + n0;

    // stage W fragments: native A[row][k = kb*16 + 8*hf + j], j=0..7
    #pragma unroll
    for (int i = 0; i < 3; ++i) {
        const int e  = tid + i * 256;
        const int rg = e >> 8;
        const int kb = (e >> 6) & 3;
        const int r  = e & 31;
        const int hf = (e >> 5) & 1;
        const int k0 = kb * 16 + hf * 8;
        float4 w0 = make_float4(0.f, 0.f, 0.f, 0.f), w1 = w0;
        if (rg == 0)      { w0 = *(const float4*)(Wv + r * 64 + k0);
                            w1 = *(const float4*)(Wv + r * 64 + k0 + 4); }
        else if (rg == 1) { w0 = *(const float4*)(Wv + (32 + r) * 64 + k0);
                            w1 = *(const float4*)(Wv + (32 + r) * 64 + k0 + 4); }
        else if (r < 8)   { w0 = *(const float4*)(Wq + r * 64 + k0);
                            w1 = *(const float4*)(Wq + r * 64 + k0 + 4); }
        else if (r < 16) {
            w0 = *(const float4*)(Wk + (r - 8) * 64 + k0);
            w1 = *(const float4*)(Wk + (r - 8) * 64 + k0 + 4);
            const float s = 1.4426950408889634f;   // fold log2(e) into g
            w0.x *= s; w0.y *= s; w0.z *= s; w0.w *= s;
            w1.x *= s; w1.y *= s; w1.z *= s; w1.w *= s;
        }
        v4u d;
        d.x = bf16pair(w0.x, w0.y); d.y = bf16pair(w0.z, w0.w);
        d.z = bf16pair(w1.x, w1.y); d.w = bf16pair(w1.z, w1.w);
        wfragN[e] = d;
    }

    // stage x fragments: native B[col=n0+l5][k = kb*16 + 8*hh + j]
    {
        const int kb = tid >> 6;
        const int k0 = kb * 16 + hh * 8;
        float a[8];
        #pragma unroll
        for (int j = 0; j < 8; ++j) a[j] = xb[(size_t)(k0 + j) * 4096 + l5];
        v4u d;
        d.x = bf16pair(a[0], a[1]); d.y = bf16pair(a[2], a[3]);
        d.z = bf16pair(a[4], a[5]); d.w = bf16pair(a[6], a[7]);
        xfragN[tid] = d;
    }
    __syncthreads();

    if (wave < 3) {
        v16f dacc = {0.f,0.f,0.f,0.f,0.f,0.f,0.f,0.f,0.f,0.f,0.f,0.f,0.f,0.f,0.f,0.f};
        #pragma unroll
        for (int kb = 0; kb < 4; ++kb) {
            const v8s af = __builtin_bit_cast(v8s, wfragN[wave * 256 + kb * 64 + lane]);
            const v8s bf = __builtin_bit_cast(v8s, xfragN[kb * 64 + lane]);
            dacc = __builtin_amdgcn_mfma_f32_32x32x16_bf16(af, bf, dacc, 0, 0, 0);
        }
        // D: row=(r&3)+8*(r>>2)+4*hh, col=n0+l5
        if (wave < 2) {
            #pragma unroll
            for (int r = 0; r < 16; ++r) {
                const int rowD = (r & 3) + ((r >> 2) << 3) + (hh << 2);
                hbuf[(wave * 32 + rowD) * 36 + l5] = (short)bf16r(dacc[r]);
            }
        } else {
            const size_t nidx = (size_t)b * 4096 + n0 + l5;
            v2u f; f.x = bf16pair(dacc[0], dacc[1]); f.y = bf16pair(dacc[2], dacc[3]);
            v2u g; g.x = bf16pair(dacc[4], dacc[5]); g.y = bf16pair(dacc[6], dacc[7]);
            *(v2u*)(ftgt + nidx * 4 + hh * 2) = f;
            *(v2u*)(ftgt + 131072 + nidx * 4 + hh * 2) = g;
        }
    }
    __syncthreads();

    // assemble hswz: t = chunk*128 + ct*64 + hh2*32 + lp ->
    // h[c=ct*32+lp][n=chunk*16+hh2*8+j], 16 contiguous bytes
    const int chunk = tid >> 7;
    const int ct    = (tid >> 6) & 1;
    const int hh2   = (tid >> 5) & 1;
    const int lp    = tid & 31;
    const short* src = hbuf + (ct * 32 + lp) * 36 + chunk * 16 + hh2 * 8;
    const v2u lo = *(const v2u*)(src);
    const v2u hi = *(const v2u*)(src + 4);
    v4u o; o.x = lo.x; o.y = lo.y; o.z = hi.x; o.w = hi.y;
    hswz[(size_t)(b * 128 + nb) * 256 + tid] = o;
}

// ---------------- K2: fused attention, pipelined LDS staging ----------------
// grid 256 = (b<<5)|mc, m0 = mc*128. 16 waves: tile = w>>2, q = w&3.
// Wave (t,q): m-tile [m0+32t, +32) x n-quarter [q*1024, +1024), 32 steps x 32n.
__global__ __launch_bounds__(1024) void attn_kernel(
    const v4u* __restrict__ ft16,     // [b][n] 16B rows (8 bf16)
    const v4u* __restrict__ gt16,
    const char* __restrict__ hswz,
    const float* __restrict__ x,
    const float* __restrict__ gamma,
    float* __restrict__ out)
{
    // 2 staging buffers x (16 KB V + 2 KB K) = 36864 B; epilogue aliases.
    __shared__ char smem[36864];
    float* ldsO = (float*)smem;              // [128 m][65] = 33280 B
    float* ldsL = (float*)(smem + 33280);    // [128 m]

    const int blk  = blockIdx.x;
    const int b    = blk >> 5;
    const int m0   = (blk & 31) << 7;
    const int tid  = threadIdx.x;
    const int wave = tid >> 6;
    const int tile = wave >> 2;
    const int q    = wave & 3;
    const int lane = tid & 63;
    const int l5   = lane & 31;
    const int hh   = lane >> 5;

    // tau: swap row-groups 4-7<->8-11 and 20-23<->24-27 (loop-invariant)
    int krow = l5;
    if (((l5 >> 2) ^ (l5 >> 3)) & 1) krow = l5 ^ 12;

    // Q B-frag: col m = m0+32*tile+l5, k=8*hh+j. hh=1 half is K-padding -> 0.
    v8s qf = __builtin_bit_cast(v8s, gt16[(size_t)b * 4096 + m0 + tile * 32 + l5]);
    if (hh) qf = (v8s)0;

    // ones B-frag for the lsum mfma (accL += P * 1)
    v4u onesu; onesu.x = 0x3F803F80u; onesu.y = 0x3F803F80u;
    onesu.z = 0x3F803F80u; onesu.w = 0x3F803F80u;
    const v8s ONES = __builtin_bit_cast(v8s, onesu);

    v16f acc0 = {0.f,0.f,0.f,0.f,0.f,0.f,0.f,0.f,0.f,0.f,0.f,0.f,0.f,0.f,0.f,0.f};
    v16f acc1 = acc0, accL = acc0;

    // staging maps (thread-flat)
    const char* hv = hswz + (size_t)b * 524288;
    const int sq   = tid >> 8;                       // V quarter staged
    const int soff = (tid & 255) * 16;
    const size_t ftbase = (size_t)b * 4096 + (tid >> 5) * 1024 + (tid & 31);

    v4u VA, KA, VB, KB;
    auto issue_loads = [&](int s, v4u& V, v4u& K) {
        V = *(const v4u*)(hv + (size_t)(sq * 32 + s) * 4096 + soff);
        if (tid < 128) K = ft16[ftbase + s * 32];
    };
    auto write_stage = [&](int bi, const v4u& V, const v4u& K) {
        *(v4u*)(smem + bi * 18432 + sq * 4096 + soff) = V;
        if (tid < 128) *(v4u*)(smem + bi * 18432 + 16384 + tid * 16) = K;
    };
    auto compute = [&](int bi) {
        const char* base = smem + bi * 18432;
        const v8s kf = __builtin_bit_cast(v8s,
            *(const v4u*)(base + 16384 + q * 512 + krow * 16));
        const char* vbuf = base + q * 4096 + lane * 16;
        const v8s V00 = __builtin_bit_cast(v8s, *(const v4u*)(vbuf));
        const v8s V01 = __builtin_bit_cast(v8s, *(const v4u*)(vbuf + 1024));
        const v8s V10 = __builtin_bit_cast(v8s, *(const v4u*)(vbuf + 2048));
        const v8s V11 = __builtin_bit_cast(v8s, *(const v4u*)(vbuf + 3072));

        v16f z = {0.f,0.f,0.f,0.f,0.f,0.f,0.f,0.f,0.f,0.f,0.f,0.f,0.f,0.f,0.f,0.f};
        v16f sc = __builtin_amdgcn_mfma_f32_32x32x16_bf16(kf, qf, z, 0, 0, 0);
        // after tau: sc[0..7] = P(n_loc=8hh+r), sc[8..15] = n_loc 16..31

        float p[8];
        v4u a;
        #pragma unroll
        for (int j = 0; j < 8; ++j) p[j] = __builtin_amdgcn_exp2f(sc[j]);
        a.x = packt(p[0], p[1]); a.y = packt(p[2], p[3]);
        a.z = packt(p[4], p[5]); a.w = packt(p[6], p[7]);
        const v8s pA0 = __builtin_bit_cast(v8s, a);     // n_loc 0-15
        accL = __builtin_amdgcn_mfma_f32_32x32x16_bf16(pA0, ONES, accL, 0, 0, 0);
        acc0 = __builtin_amdgcn_mfma_f32_32x32x16_bf16(pA0, V00, acc0, 0, 0, 0);
        acc1 = __builtin_amdgcn_mfma_f32_32x32x16_bf16(pA0, V01, acc1, 0, 0, 0);

        #pragma unroll
        for (int j = 0; j < 8; ++j) p[j] = __builtin_amdgcn_exp2f(sc[8 + j]);
        a.x = packt(p[0], p[1]); a.y = packt(p[2], p[3]);
        a.z = packt(p[4], p[5]); a.w = packt(p[6], p[7]);
        const v8s pA1 = __builtin_bit_cast(v8s, a);     // n_loc 16-31
        accL = __builtin_amdgcn_mfma_f32_32x32x16_bf16(pA1, ONES, accL, 0, 0, 0);
        acc0 = __builtin_amdgcn_mfma_f32_32x32x16_bf16(pA1, V10, acc0, 0, 0, 0);
        acc1 = __builtin_amdgcn_mfma_f32_32x32x16_bf16(pA1, V11, acc1, 0, 0, 0);
    };

    // prologue: loads for steps 0,1 in flight; buf0 <- step 0
    issue_loads(0, VA, KA);
    issue_loads(1, VB, KB);
    write_stage(0, VA, KA);
    __syncthreads();

    for (int s = 0; s < 32; s += 2) {
        if (s + 2 < 32) issue_loads(s + 2, VA, KA);   // 2-step-ahead prefetch
        compute(0);
        if (s + 1 < 32) write_stage(1, VB, KB);       // issued at s-1: ~1.5 steps old
        __syncthreads();

        if (s + 3 < 32) issue_loads(s + 3, VB, KB);
        compute(1);
        if (s + 2 < 32) write_stage(0, VA, KA);
        __syncthreads();
    }

    // combine 4 quarters per tile: q0 writes, q1-3 add (aliased over staging)
    // accL[r] = lsum for m-row rowD(r,hh) (replicated across l5)
    if (q == 0) {
        #pragma unroll
        for (int r = 0; r < 16; ++r) {
            const int rowD = (r & 3) + ((r >> 2) << 3) + (hh << 2);
            ldsO[(tile * 32 + rowD) * 65 + l5]      = acc0[r];
            ldsO[(tile * 32 + rowD) * 65 + 32 + l5] = acc1[r];
            if (l5 == 0) ldsL[tile * 32 + rowD] = accL[r];
        }
    }
    __syncthreads();
    #pragma unroll
    for (int ph = 1; ph < 4; ++ph) {
        if (q == ph) {
            #pragma unroll
            for (int r = 0; r < 16; ++r) {
                const int rowD = (r & 3) + ((r >> 2) << 3) + (hh << 2);
                ldsO[(tile * 32 + rowD) * 65 + l5]      += acc0[r];
                ldsO[(tile * 32 + rowD) * 65 + 32 + l5] += acc1[r];
                if (l5 == 0) ldsL[tile * 32 + rowD] += accL[r];
            }
        }
        __syncthreads();
    }

    // final: normalize + gamma*o + x, coalesced over m (128 consecutive)
    const float gam = gamma[0];
    const int m  = tid & 127;
    const int c0 = (tid >> 7) * 8;
    const float rL = 1.0f / ldsL[m];
    #pragma unroll
    for (int k = 0; k < 8; ++k) {
        const int c = c0 + k;
        const float O = ldsO[m * 65 + c];
        const size_t idx = ((size_t)b * 64 + c) * 4096 + m0 + m;
        out[idx] = gam * (O * rL) + x[idx];
    }
}

extern "C" void kernel_launch(void* const* d_in, const int* in_sizes, int n_in,
                              void* d_out, int out_size, void* d_ws, size_t ws_size,
                              hipStream_t stream) {
    const float* x     = (const float*)d_in[0];
    const float* Wq    = (const float*)d_in[1];
    const float* Wk    = (const float*)d_in[2];
    const float* Wv    = (const float*)d_in[3];
    const float* gamma = (const float*)d_in[4];
    float* out = (float*)d_out;

    unsigned int* ftgt = (unsigned int*)d_ws;   // ft 512KB + gt 512KB
    v4u* hswz = (v4u*)(ftgt + 262144);          // 4MB fragment-swizzled h

    hipLaunchKernelGGL(fgh_kernel, dim3(1024), dim3(256), 0, stream,
                       x, Wq, Wk, Wv, ftgt, hswz);
    hipLaunchKernelGGL(attn_kernel, dim3(256), dim3(1024), 0, stream,
                       (const v4u*)ftgt, (const v4u*)(ftgt + 131072),
                       (const char*)hswz, x, gamma, out);
}

// Round 9
// 97.624 us; speedup vs baseline: 1.0511x; 1.0511x over previous
//
#include <hip/hip_runtime.h>
#include <hip/hip_bf16.h>
#include <stdint.h>

// SelfAttention: B=8, C=64, N=4096, d_k=8.
// out[b,c,m] = gamma * (sum_n h[b,c,n] * softmax_n(f[:,n].g[:,m])) + x[b,c,m]
//
// R9: R8 post-mortem showed the compiler sank register prefetches (VGPR 56),
// so every barrier's vmcnt(0) drain ate full L2 latency (~2200 cyc/step).
// Now staging uses __builtin_amdgcn_global_load_lds (async DMA, un-sinkable):
//   per step: issue stage(s+1) -> buf^1 (async), compute(s) from buf (~2000
//   cyc), one __syncthreads (its vmcnt drain finds loads landed). 16 steps of
//   64-n, 72 KB double-buffered LDS, 1 block/CU.
// grid 256 = (b<<5)|mc, m0 = mc*128. 16 waves: tile = w>>2 (m), q = w&3 (n).
//   QK: native 32x32x16, K padded 8->16 (qf zeroed in hh=1 lanes).
//   tau row-permute (krow = l5^12 on row-groups 4-7<->8-11, 20-23<->24-27)
//   makes S^T regs 0..7/8..15 pack sequentially into PV A-frags (no shuffles).
// hswz (V) layout per 32-n tile (4096 B), 32x32x16 B-frag order:
//   offset = chunk*2048 + ct*1024 + (hh*32+l5)*16 holding
//   h[c=ct*32+l5][n = nb*32 + chunk*16 + 8*hh + j], j=0..7.
// K1 (fgh): MFMA projection (x read once), native 32x32x16 K-loop.

typedef short v4s __attribute__((ext_vector_type(4)));
typedef short v8s __attribute__((ext_vector_type(8)));
typedef float v16f __attribute__((ext_vector_type(16)));
typedef unsigned int v4u __attribute__((ext_vector_type(4)));
typedef unsigned int v2u __attribute__((ext_vector_type(2)));

typedef __attribute__((address_space(3))) char lds_char;
typedef __attribute__((address_space(1))) const char g_char;

__device__ __forceinline__ void gld16(g_char* g, lds_char* l) {
    __builtin_amdgcn_global_load_lds((const __attribute__((address_space(1))) unsigned int*)g,
                                     (__attribute__((address_space(3))) unsigned int*)l,
                                     16, 0, 0);
}

__device__ __forceinline__ unsigned bf16pair(float lo, float hi) {
    unsigned a = __builtin_bit_cast(unsigned, lo) + 0x8000u;
    unsigned b = __builtin_bit_cast(unsigned, hi) + 0x8000u;
    return (a >> 16) | (b & 0xffff0000u);
}
__device__ __forceinline__ unsigned short bf16r(float x) {
    return (unsigned short)((__builtin_bit_cast(unsigned, x) + 0x8000u) >> 16);
}
// truncating bf16 pack via v_perm: dword = [hi16(hi) | hi16(lo)]
__device__ __forceinline__ unsigned packt(float lo, float hi) {
    return __builtin_amdgcn_perm(__builtin_bit_cast(unsigned, hi),
                                 __builtin_bit_cast(unsigned, lo), 0x07060302u);
}

// ---------------- K1: MFMA projection ----------------
// grid 1024 = (b<<7)|nb. Wave w<2: h rows w*32..+31; wave 2: f(0-7)+g(8-15).
__global__ __launch_bounds__(256) void fgh_kernel(
    const float* __restrict__ x, const float* __restrict__ Wq,
    const float* __restrict__ Wk, const float* __restrict__ Wv,
    unsigned int* __restrict__ ftgt,   // ft dwords [0,131072), gt [131072,262144)
    v4u* __restrict__ hswz)
{
    __shared__ v4u wfragN[768];        // 3 row-groups x 4 kb x 64 lanes x 16B
    __shared__ v4u xfragN[256];        // 4 kb x 64 lanes x 16B
    __shared__ short hbuf[64 * 36];    // [c][nloc] pad 36

    const int blk  = blockIdx.x;
    const int b    = blk >> 7;
    const int nb   = blk & 127;
    const int n0   = nb << 5;
    const int tid  = threadIdx.x;
    const int wave = tid >> 6;
    const int lane = tid & 63;
    const int l5   = lane & 31;
    const int hh   = lane >> 5;

    const float* xb = x + (size_t)b * 262144 + n0;

    // stage W fragments: native A[row][k = kb*16 + 8*hf + j], j=0..7
    #pragma unroll
    for (int i = 0; i < 3; ++i) {
        const int e  = tid + i * 256;
        const int rg = e >> 8;
        const int kb = (e >> 6) & 3;
        const int r  = e & 31;
        const int hf = (e >> 5) & 1;
        const int k0 = kb * 16 + hf * 8;
        float4 w0 = make_float4(0.f, 0.f, 0.f, 0.f), w1 = w0;
        if (rg == 0)      { w0 = *(const float4*)(Wv + r * 64 + k0);
                            w1 = *(const float4*)(Wv + r * 64 + k0 + 4); }
        else if (rg == 1) { w0 = *(const float4*)(Wv + (32 + r) * 64 + k0);
                            w1 = *(const float4*)(Wv + (32 + r) * 64 + k0 + 4); }
        else if (r < 8)   { w0 = *(const float4*)(Wq + r * 64 + k0);
                            w1 = *(const float4*)(Wq + r * 64 + k0 + 4); }
        else if (r < 16) {
            w0 = *(const float4*)(Wk + (r - 8) * 64 + k0);
            w1 = *(const float4*)(Wk + (r - 8) * 64 + k0 + 4);
            const float s = 1.4426950408889634f;   // fold log2(e) into g
            w0.x *= s; w0.y *= s; w0.z *= s; w0.w *= s;
            w1.x *= s; w1.y *= s; w1.z *= s; w1.w *= s;
        }
        v4u d;
        d.x = bf16pair(w0.x, w0.y); d.y = bf16pair(w0.z, w0.w);
        d.z = bf16pair(w1.x, w1.y); d.w = bf16pair(w1.z, w1.w);
        wfragN[e] = d;
    }

    // stage x fragments: native B[col=n0+l5][k = kb*16 + 8*hh + j]
    {
        const int kb = tid >> 6;
        const int k0 = kb * 16 + hh * 8;
        float a[8];
        #pragma unroll
        for (int j = 0; j < 8; ++j) a[j] = xb[(size_t)(k0 + j) * 4096 + l5];
        v4u d;
        d.x = bf16pair(a[0], a[1]); d.y = bf16pair(a[2], a[3]);
        d.z = bf16pair(a[4], a[5]); d.w = bf16pair(a[6], a[7]);
        xfragN[tid] = d;
    }
    __syncthreads();

    if (wave < 3) {
        v16f dacc = {0.f,0.f,0.f,0.f,0.f,0.f,0.f,0.f,0.f,0.f,0.f,0.f,0.f,0.f,0.f,0.f};
        #pragma unroll
        for (int kb = 0; kb < 4; ++kb) {
            const v8s af = __builtin_bit_cast(v8s, wfragN[wave * 256 + kb * 64 + lane]);
            const v8s bf = __builtin_bit_cast(v8s, xfragN[kb * 64 + lane]);
            dacc = __builtin_amdgcn_mfma_f32_32x32x16_bf16(af, bf, dacc, 0, 0, 0);
        }
        // D: row=(r&3)+8*(r>>2)+4*hh, col=n0+l5
        if (wave < 2) {
            #pragma unroll
            for (int r = 0; r < 16; ++r) {
                const int rowD = (r & 3) + ((r >> 2) << 3) + (hh << 2);
                hbuf[(wave * 32 + rowD) * 36 + l5] = (short)bf16r(dacc[r]);
            }
        } else {
            const size_t nidx = (size_t)b * 4096 + n0 + l5;
            v2u f; f.x = bf16pair(dacc[0], dacc[1]); f.y = bf16pair(dacc[2], dacc[3]);
            v2u g; g.x = bf16pair(dacc[4], dacc[5]); g.y = bf16pair(dacc[6], dacc[7]);
            *(v2u*)(ftgt + nidx * 4 + hh * 2) = f;
            *(v2u*)(ftgt + 131072 + nidx * 4 + hh * 2) = g;
        }
    }
    __syncthreads();

    // assemble hswz: t = chunk*128 + ct*64 + hh2*32 + lp ->
    // h[c=ct*32+lp][n=chunk*16+hh2*8+j], 16 contiguous bytes
    const int chunk = tid >> 7;
    const int ct    = (tid >> 6) & 1;
    const int hh2   = (tid >> 5) & 1;
    const int lp    = tid & 31;
    const short* src = hbuf + (ct * 32 + lp) * 36 + chunk * 16 + hh2 * 8;
    const v2u lo = *(const v2u*)(src);
    const v2u hi = *(const v2u*)(src + 4);
    v4u o; o.x = lo.x; o.y = lo.y; o.z = hi.x; o.w = hi.y;
    hswz[(size_t)(b * 128 + nb) * 256 + tid] = o;
}

// ---------------- K2: fused attention, async-LDS staging ----------------
// grid 256 = (b<<5)|mc, m0 = mc*128. 16 waves: tile = w>>2, q = w&3.
// 16 steps x 64-n. LDS: 2 bufs x (32 KB V + 4 KB K) = 73728 B; epilogue aliases.
__global__ __launch_bounds__(1024) void attn_kernel(
    const v4u* __restrict__ ft16,     // [b][n] 16B rows (8 bf16)
    const v4u* __restrict__ gt16,
    const char* __restrict__ hswz,
    const float* __restrict__ x,
    const float* __restrict__ gamma,
    float* __restrict__ out)
{
    __shared__ char smem[73728];
    float* ldsO = (float*)smem;              // [128 m][65] = 33280 B (epilogue)
    float* ldsL = (float*)(smem + 33280);    // [128 m]
    lds_char* lds = (lds_char*)smem;

    const int blk  = blockIdx.x;
    const int b    = blk >> 5;
    const int m0   = (blk & 31) << 7;
    const int tid  = threadIdx.x;
    const int wave = tid >> 6;
    const int tile = wave >> 2;       // m-tile role
    const int q    = wave & 3;        // n-quarter role
    const int lane = tid & 63;
    const int l5   = lane & 31;
    const int hh   = lane >> 5;

    // tau: swap row-groups 4-7<->8-11 and 20-23<->24-27 (loop-invariant)
    int krow = l5;
    if (((l5 >> 2) ^ (l5 >> 3)) & 1) krow = l5 ^ 12;

    // Q B-frag: col m = m0+32*tile+l5, k=8*hh+j. hh=1 half is K-padding -> 0.
    v8s qf = __builtin_bit_cast(v8s, gt16[(size_t)b * 4096 + m0 + tile * 32 + l5]);
    if (hh) qf = (v8s)0;

    v16f acc0 = {0.f,0.f,0.f,0.f,0.f,0.f,0.f,0.f,0.f,0.f,0.f,0.f,0.f,0.f,0.f,0.f};
    v16f acc1 = acc0;
    float lsum = 0.f;

    // staging roles (independent of compute roles; barrier separates them)
    // V: wave stages quarter sq = wave>>2, sub-2KB block sub = wave&3,
    //    two 1KB gld16 ops. K: waves 0-3 stage quarter `wave` (1 KB).
    const int sq  = wave >> 2;
    const int sub = wave & 3;
    g_char* hv_g = (g_char*)(hswz + (size_t)b * 524288);
    g_char* vsrc0 = hv_g + (size_t)sq * 131072 + sub * 2048 + lane * 16;
    lds_char* vdst0 = lds + sq * 8192 + sub * 2048 + lane * 16;
    g_char* ksrc0 = (g_char*)(ft16 + (size_t)b * 4096 + wave * 1024 + lane);
    lds_char* kdst0 = lds + 32768 + wave * 1024 + lane * 16;

    // prologue: stage step 0 into buf 0; barrier drain covers it (once)
    gld16(vsrc0, vdst0);
    gld16(vsrc0 + 1024, vdst0 + 1024);
    if (wave < 4) gld16(ksrc0, kdst0);
    __syncthreads();

    for (int s = 0; s < 16; ++s) {
        const int buf  = s & 1;
        const int nbuf = buf ^ 1;
        // issue next step's async staging (lands during compute)
        if (s + 1 < 16) {
            gld16(vsrc0 + (size_t)(s + 1) * 8192, vdst0 + nbuf * 36864);
            gld16(vsrc0 + (size_t)(s + 1) * 8192 + 1024, vdst0 + nbuf * 36864 + 1024);
            if (wave < 4) gld16(ksrc0 + (size_t)(s + 1) * 1024, kdst0 + nbuf * 36864);
        }

        // compute 2 x 32-n tiles from buf
        const char* base = smem + buf * 36864;
        #pragma unroll
        for (int h2 = 0; h2 < 2; ++h2) {
            const v8s kf = __builtin_bit_cast(v8s,
                *(const v4u*)(base + 32768 + q * 1024 + h2 * 512 + krow * 16));
            const char* vt = base + q * 8192 + h2 * 4096 + lane * 16;
            const v8s V00 = __builtin_bit_cast(v8s, *(const v4u*)(vt));
            const v8s V01 = __builtin_bit_cast(v8s, *(const v4u*)(vt + 1024));
            const v8s V10 = __builtin_bit_cast(v8s, *(const v4u*)(vt + 2048));
            const v8s V11 = __builtin_bit_cast(v8s, *(const v4u*)(vt + 3072));

            v16f z = {0.f,0.f,0.f,0.f,0.f,0.f,0.f,0.f,0.f,0.f,0.f,0.f,0.f,0.f,0.f,0.f};
            v16f sc = __builtin_amdgcn_mfma_f32_32x32x16_bf16(kf, qf, z, 0, 0, 0);
            // after tau: sc[0..7] = P(n_loc=8hh+r), sc[8..15] = n_loc 16..31

            float p[16];
            #pragma unroll
            for (int j = 0; j < 16; ++j) p[j] = __builtin_amdgcn_exp2f(sc[j]);
            #pragma unroll
            for (int j = 0; j < 16; ++j) lsum += p[j];

            v4u a0, a1;
            a0.x = packt(p[0], p[1]);   a0.y = packt(p[2], p[3]);
            a0.z = packt(p[4], p[5]);   a0.w = packt(p[6], p[7]);
            a1.x = packt(p[8], p[9]);   a1.y = packt(p[10], p[11]);
            a1.z = packt(p[12], p[13]); a1.w = packt(p[14], p[15]);
            const v8s pA0 = __builtin_bit_cast(v8s, a0);    // n_loc 0-15
            const v8s pA1 = __builtin_bit_cast(v8s, a1);    // n_loc 16-31

            acc0 = __builtin_amdgcn_mfma_f32_32x32x16_bf16(pA0, V00, acc0, 0, 0, 0);
            acc1 = __builtin_amdgcn_mfma_f32_32x32x16_bf16(pA0, V01, acc1, 0, 0, 0);
            acc0 = __builtin_amdgcn_mfma_f32_32x32x16_bf16(pA1, V10, acc0, 0, 0, 0);
            acc1 = __builtin_amdgcn_mfma_f32_32x32x16_bf16(pA1, V11, acc1, 0, 0, 0);
        }
        __syncthreads();   // vmcnt drain: next step's loads landed during compute
    }

    // fold lane/lane+32 (same m, disjoint n)
    lsum += __shfl_xor(lsum, 32);

    // combine 4 quarters per tile: q0 writes, q1-3 add (aliased over staging)
    if (q == 0) {
        #pragma unroll
        for (int r = 0; r < 16; ++r) {
            const int rowD = (r & 3) + ((r >> 2) << 3) + (hh << 2);
            ldsO[(tile * 32 + rowD) * 65 + l5]      = acc0[r];
            ldsO[(tile * 32 + rowD) * 65 + 32 + l5] = acc1[r];
        }
        if (hh == 0) ldsL[tile * 32 + l5] = lsum;
    }
    __syncthreads();
    #pragma unroll
    for (int ph = 1; ph < 4; ++ph) {
        if (q == ph) {
            #pragma unroll
            for (int r = 0; r < 16; ++r) {
                const int rowD = (r & 3) + ((r >> 2) << 3) + (hh << 2);
                ldsO[(tile * 32 + rowD) * 65 + l5]      += acc0[r];
                ldsO[(tile * 32 + rowD) * 65 + 32 + l5] += acc1[r];
            }
            if (hh == 0) ldsL[tile * 32 + l5] += lsum;
        }
        __syncthreads();
    }

    // final: normalize + gamma*o + x, coalesced over m (128 consecutive)
    const float gam = gamma[0];
    const int m  = tid & 127;
    const int c0 = (tid >> 7) * 8;
    const float rL = 1.0f / ldsL[m];
    #pragma unroll
    for (int k = 0; k < 8; ++k) {
        const int c = c0 + k;
        const float O = ldsO[m * 65 + c];
        const size_t idx = ((size_t)b * 64 + c) * 4096 + m0 + m;
        out[idx] = gam * (O * rL) + x[idx];
    }
}

extern "C" void kernel_launch(void* const* d_in, const int* in_sizes, int n_in,
                              void* d_out, int out_size, void* d_ws, size_t ws_size,
                              hipStream_t stream) {
    const float* x     = (const float*)d_in[0];
    const float* Wq    = (const float*)d_in[1];
    const float* Wk    = (const float*)d_in[2];
    const float* Wv    = (const float*)d_in[3];
    const float* gamma = (const float*)d_in[4];
    float* out = (float*)d_out;

    unsigned int* ftgt = (unsigned int*)d_ws;   // ft 512KB + gt 512KB
    v4u* hswz = (v4u*)(ftgt + 262144);          // 4MB fragment-swizzled h

    hipLaunchKernelGGL(fgh_kernel, dim3(1024), dim3(256), 0, stream,
                       x, Wq, Wk, Wv, ftgt, hswz);
    hipLaunchKernelGGL(attn_kernel, dim3(256), dim3(1024), 0, stream,
                       (const v4u*)ftgt, (const v4u*)(ftgt + 131072),
                       (const char*)hswz, x, gamma, out);
}